// Round 13
// baseline (379.191 us; speedup 1.0000x reference)
//
#include <hip/hip_runtime.h>
#include <hip/hip_bf16.h>

using bf16 = __hip_bfloat16;
typedef __attribute__((ext_vector_type(8))) short bf16x8;
typedef __attribute__((ext_vector_type(4))) float f32x4;

#define NB   1024
#define TT   14
#define DM   1024
#define ROWS (NB*TT)   // 14336
#define NCAT 1280      // 1216 padded to 10*128

__device__ __forceinline__ unsigned short f2b(float f) {
  union { bf16 h; unsigned short u; } cv; cv.h = __float2bfloat16(f); return cv.u;
}

__device__ __forceinline__ void gload16(const bf16* g, bf16* l) {
  __builtin_amdgcn_global_load_lds((const __attribute__((address_space(1))) void*)g,
                                   (__attribute__((address_space(3))) void*)l, 16, 0, 0);
}

// ---- one-shot prep: weight transposes + converts + biases + x->bf16 --------
__global__ __launch_bounds__(256) void k_prep_all(
    const float* __restrict__ x_in,
    const float* __restrict__ Wv, const float* __restrict__ Wo,
    const float* __restrict__ Wa, const float* __restrict__ Wproj,
    const float* __restrict__ Wout,
    const float* __restrict__ bv, const float* __restrict__ bo,
    const float* __restrict__ ba, const float* __restrict__ b_out,
    const float* __restrict__ b_proj,
    bf16* __restrict__ x_bf,
    bf16* __restrict__ wcat_t, bf16* __restrict__ wproj_t,
    bf16* __restrict__ wout_b, float* __restrict__ bcat,
    float* __restrict__ bcomb) {
  __shared__ float t[32][33];
  const int x = blockIdx.x, y = blockIdx.y;
  const int lx = threadIdx.x & 31, ly = threadIdx.x >> 5;
  if (y < 72) {
    const float* src; bf16* dst; int base, width;
    if (y < 40) {
      dst = wcat_t;
      int n0 = y * 32;
      if (n0 < 1024)      { src = Wv; base = 0;    width = 1024; }
      else if (n0 < 1152) { src = Wo; base = 1024; width = 128;  }
      else if (n0 < 1216) { src = Wa; base = 1152; width = 64;   }
      else                { src = nullptr; base = 0; width = 1;  }
      int k0 = x * 32, n0b = n0;
#pragma unroll
      for (int r = 0; r < 32; r += 8)
        t[ly + r][lx] = src ? src[(size_t)(k0 + ly + r) * width + (n0b - base + lx)] : 0.0f;
      __syncthreads();
#pragma unroll
      for (int r = 0; r < 32; r += 8)
        dst[(size_t)(n0b + ly + r) * 1024 + (k0 + lx)] = __float2bfloat16(t[lx][ly + r]);
    } else {
      int n0 = (y - 40) * 32, k0 = x * 32;
#pragma unroll
      for (int r = 0; r < 32; r += 8)
        t[ly + r][lx] = Wproj[(size_t)(k0 + ly + r) * 1024 + (n0 + lx)];
      __syncthreads();
#pragma unroll
      for (int r = 0; r < 32; r += 8)
        wproj_t[(size_t)(n0 + ly + r) * 1024 + (k0 + lx)] = __float2bfloat16(t[lx][ly + r]);
    }
  } else if (y < 80) {
    int i0 = ((y - 72) * 32 + x) * 1024 + threadIdx.x;
#pragma unroll
    for (int r = 0; r < 4; ++r) {
      int i = i0 + r * 256;
      float4 v = reinterpret_cast<const float4*>(Wout)[i];
      ushort4 o;
      o.x = f2b(v.x); o.y = f2b(v.y); o.z = f2b(v.z); o.w = f2b(v.w);
      reinterpret_cast<ushort4*>(wout_b)[i] = o;
    }
  } else if (y == 80) {
    if (x < 5) {
      int i = x * 256 + threadIdx.x;
      if (i < NCAT) {
        float v = 0.0f;
        if (i < 1024) v = bv[i];
        else if (i < 1152) v = bo[i - 1024];
        else if (i < 1216) v = ba[i - 1152];
        bcat[i] = v;
      }
    } else if (x < 21) {
      __shared__ float part[4][64];
      int j0 = (x - 5) * 64;
      int jl = threadIdx.x & 63, ip = threadIdx.x >> 6;
      int j = j0 + jl;
      float acc = 0.0f;
      int i0 = ip * 256;
      for (int i = i0; i < i0 + 256; ++i)
        acc = fmaf(b_out[i], Wproj[(size_t)i * 1024 + j], acc);
      part[ip][jl] = acc;
      __syncthreads();
      if (threadIdx.x < 64) {
        int jj = j0 + threadIdx.x;
        bcomb[jj] = part[0][threadIdx.x] + part[1][threadIdx.x] +
                    part[2][threadIdx.x] + part[3][threadIdx.x] + b_proj[jj];
      }
    }
  } else {
    int id = (y - 81) * 32 + x;
    int i0 = id * 2048 + threadIdx.x;
#pragma unroll
    for (int r = 0; r < 8; ++r) {
      int i = i0 + r * 256;
      float4 v = reinterpret_cast<const float4*>(x_in)[i];
      ushort4 o;
      o.x = f2b(v.x); o.y = f2b(v.y); o.z = f2b(v.z); o.w = f2b(v.w);
      reinterpret_cast<ushort4*>(x_bf)[i] = o;
    }
  }
}

// ------------------- dual-job bf16 MFMA GEMM (B^T), 128² tile ----------------
// High-occupancy variant of the measured-best structure: DOUBLE-buffered LDS
// (32 KB -> 5 blocks/CU, 20 waves/CU), counted vmcnt(4) preserved via the
// reordered loop {vmcnt(4); bar; COMPUTE(cur); bar; STAGE(cur, i+2)} — tile
// i+2's loads issued into the buffer all waves just finished reading (race-
// free by the second barrier), consumed 1 full iteration later.  Zero-conflict
// LDS addressing (R11-proven pair), swapped-operand MFMA, setprio, bijective
// XCD swizzle on job1.  Job2 (blocks >= nwg1) fills the tail.
template<int OUT1, int OUT2>
__global__ __launch_bounds__(256, 5) void k_gemm_dual(
    const bf16* __restrict__ A1, const bf16* __restrict__ B1,
    void* __restrict__ C1v, const float* __restrict__ bias1,
    int N1, int K1, int lda1, int ldb1, int nx1, int nwg1,
    const bf16* __restrict__ A2, const bf16* __restrict__ B2,
    void* __restrict__ C2v, const float* __restrict__ bias2,
    int N2, int K2, int lda2, int ldb2, int nx2) {
  constexpr int ASZ = 4096, BSZ = 4096;   // 128 rows x 32 k per buffer
  __shared__ bf16 As[2 * ASZ];
  __shared__ bf16 Bs[2 * BSZ];

  const int tid  = threadIdx.x;
  const int wave = tid >> 6, lane = tid & 63;

  const bf16 *A, *Bt; void* Cv; const float* bias;
  int N, K, lda, ldb, bx, by; bool ob;
  if ((int)blockIdx.x < nwg1) {
    int bid = blockIdx.x;
    int q = nwg1 >> 3, r = nwg1 & 7;
    int xcd = bid & 7, li = bid >> 3;
    bid = (xcd < r ? xcd * (q + 1) : r * (q + 1) + (xcd - r) * q) + li;
    A = A1; Bt = B1; Cv = C1v; bias = bias1;
    N = N1; K = K1; lda = lda1; ldb = ldb1;
    bx = bid % nx1; by = bid / nx1; ob = (OUT1 != 0);
  } else {
    int bid = blockIdx.x - nwg1;
    A = A2; Bt = B2; Cv = C2v; bias = bias2;
    N = N2; K = K2; lda = lda2; ldb = ldb2;
    bx = bid % nx2; by = bid / nx2; ob = (OUT2 != 0);
  }
  const int row0 = by * 128, col0 = bx * 128;
  const int wr = (wave >> 1) * 64, wc = (wave & 1) * 64;
  f32x4 acc[4][4] = {};

  // staging source: pre-swizzled slot so linear LDS dest == swizzled layout
  const int sr  = tid >> 2;
  const int scb = (tid & 3) ^ ((tid >> 3) & 3);
  const bf16* Ab = A  + (size_t)(row0 + sr) * lda + scb * 8;
  const bf16* Bb = Bt + (size_t)(col0 + sr) * ldb + scb * 8;

  // read offsets: lane-constant swizzled slot fs (zero-conflict pair, R11)
  const int fr = lane & 15, g = lane >> 4;
  const int fs = (g ^ ((fr >> 1) & 3)) * 8;
  int aoff[4], boff[4];
#pragma unroll
  for (int mi = 0; mi < 4; ++mi) {
    int row = wr + mi * 16 + fr, h = row >> 6, lr = row & 63;
    aoff[mi] = h * 2048 + lr * 32 + fs;
  }
#pragma unroll
  for (int ni = 0; ni < 4; ++ni) {
    int row = wc + ni * 16 + fr, h = row >> 6, lr = row & 63;
    boff[ni] = h * 2048 + lr * 32 + fs;
  }

  auto STAGE = [&](int s, int kk) {
    const int ko = kk * 32;
#pragma unroll
    for (int j = 0; j < 2; ++j)
      gload16(Ab + (size_t)j * 64 * lda + ko, As + s * ASZ + j * 2048 + tid * 8);
#pragma unroll
    for (int j = 0; j < 2; ++j)
      gload16(Bb + (size_t)j * 64 * ldb + ko, Bs + s * BSZ + j * 2048 + tid * 8);
  };
  auto COMPUTE = [&](int s) {
    const bf16* as = As + s * ASZ;
    const bf16* bs = Bs + s * BSZ;
    bf16x8 af[4], bfm[4];
#pragma unroll
    for (int mi = 0; mi < 4; ++mi) af[mi] = *(const bf16x8*)(as + aoff[mi]);
#pragma unroll
    for (int ni = 0; ni < 4; ++ni) bfm[ni] = *(const bf16x8*)(bs + boff[ni]);
    __builtin_amdgcn_s_setprio(1);
#pragma unroll
    for (int mi = 0; mi < 4; ++mi)
#pragma unroll
      for (int ni = 0; ni < 4; ++ni)   // swapped operands: acc holds C^T frag
        acc[mi][ni] = __builtin_amdgcn_mfma_f32_16x16x32_bf16(bfm[ni], af[mi], acc[mi][ni], 0, 0, 0);
    __builtin_amdgcn_s_setprio(0);
  };

  const int nk = K >> 5;
  STAGE(0, 0);
  STAGE(1, 1);
  int cur = 0;
  for (int i = 0; i < nk; ++i) {
    // ledger: outstanding = tiles {i, i+1} (8 loads); vmcnt(4) drains tile i
    if (i < nk - 1) asm volatile("s_waitcnt vmcnt(4)" ::: "memory");
    else            asm volatile("s_waitcnt vmcnt(0)" ::: "memory");
    __builtin_amdgcn_s_barrier();
    asm volatile("" ::: "memory");
    COMPUTE(cur);
    __builtin_amdgcn_s_barrier();          // all waves done reading buf cur
    asm volatile("" ::: "memory");
    if (i + 2 < nk) STAGE(cur, i + 2);     // overwrite just-freed buffer
    cur ^= 1;
  }

  // epilogue: thread holds row gr, 4 consecutive cols per fragment
  const int fq = g * 4;
#pragma unroll
  for (int mi = 0; mi < 4; ++mi) {
    int gr = row0 + wr + mi * 16 + fr;
#pragma unroll
    for (int ni = 0; ni < 4; ++ni) {
      int gc = col0 + wc + ni * 16 + fq;
      float b0 = 0, b1 = 0, b2 = 0, b3 = 0;
      if (bias) {
        float4 bv = *reinterpret_cast<const float4*>(bias + gc);
        b0 = bv.x; b1 = bv.y; b2 = bv.z; b3 = bv.w;
      }
      float v0 = acc[mi][ni][0] + b0, v1 = acc[mi][ni][1] + b1;
      float v2 = acc[mi][ni][2] + b2, v3 = acc[mi][ni][3] + b3;
      if (ob) {
        ushort4 u; u.x = f2b(v0); u.y = f2b(v1); u.z = f2b(v2); u.w = f2b(v3);
        *reinterpret_cast<ushort4*>((bf16*)Cv + (size_t)gr * N + gc) = u;
      } else {
        float4 o; o.x = v0; o.y = v1; o.z = v2; o.w = v3;
        *reinterpret_cast<float4*>((float*)Cv + (size_t)gr * N + gc) = o;
      }
    }
  }
}

// ------------------------------- sampling -----------------------------------
// C1: [ROWS][1280] bf16 = [value(1024) | off(128) | attn(64) | pad(64)] (+bias).
__global__ __launch_bounds__(512) void k_sample(const bf16* __restrict__ C1,
                                                bf16* __restrict__ y) {
  const int wave = threadIdx.x >> 6, lane = threadIdx.x & 63;
  const int row = blockIdx.x * 8 + wave;           // < 14336
  const int b = row / TT, t = row - b * TT;
  const bf16* r1 = C1 + (size_t)row * NCAT;

  float offx, offy;
  {
    ushort2 u = *reinterpret_cast<const ushort2*>(r1 + 1024 + lane * 2);
    offx = __uint_as_float(((unsigned)u.x) << 16);
    offy = __uint_as_float(((unsigned)u.y) << 16);
  }
  float logit;
  {
    unsigned short u = reinterpret_cast<const unsigned short*>(r1)[1152 + lane];
    logit = __uint_as_float(((unsigned)u) << 16);
  }
  float m = fmaxf(logit, __shfl_xor(logit, 1));
  m = fmaxf(m, __shfl_xor(m, 2));
  float e = __expf(logit - m);
  float s = e + __shfl_xor(e, 1);
  s = s + __shfl_xor(s, 2);
  float aw = e / s;

  const float refx = (float)t * (1.0f / 13.0f);
  float ix = refx + offx - 0.5f;
  float xf = floorf(ix);
  float fx = ix - xf;
  float wx = (xf == 0.0f) ? (1.0f - fx) : ((xf == -1.0f) ? fx : 0.0f);

  float iy = offy - 0.5f;
  float yf = floorf(iy);
  float fy = iy - yf;
  int y0 = (int)yf, y1 = y0 + 1;
  float w0 = (y0 >= 0 && y0 < TT) ? (1.0f - fy) : 0.0f;
  float w1 = (y1 >= 0 && y1 < TT) ? fy : 0.0f;
  int i0 = max(0, min(TT - 1, y0));
  int i1 = max(0, min(TT - 1, y1));
  float cw0 = aw * wx * w0;
  float cw1 = aw * wx * w1;

  const bf16* vb = C1 + (size_t)(b * TT) * NCAT;
  float acc[16];
#pragma unroll
  for (int h = 0; h < 16; ++h) acc[h] = 0.0f;
#pragma unroll
  for (int j = 0; j < 64; ++j) {
    float c0 = __shfl(cw0, j);
    float c1 = __shfl(cw1, j);
    int a0 = __shfl(i0, j);
    int a1 = __shfl(i1, j);
    const int hh = j >> 2;
    float v0 = __bfloat162float(vb[(size_t)a0 * NCAT + hh * 64 + lane]);
    float v1 = __bfloat162float(vb[(size_t)a1 * NCAT + hh * 64 + lane]);
    acc[hh] = fmaf(c0, v0, fmaf(c1, v1, acc[hh]));
  }
#pragma unroll
  for (int h = 0; h < 16; ++h)
    y[(size_t)row * DM + h * 64 + lane] = __float2bfloat16(acc[h]);
}

// ------------------------------- launcher -----------------------------------
extern "C" void kernel_launch(void* const* d_in, const int* in_sizes, int n_in,
                              void* d_out, int out_size, void* d_ws, size_t ws_size,
                              hipStream_t stream) {
  (void)in_sizes; (void)n_in; (void)out_size; (void)ws_size;
  const float* x       = (const float*)d_in[0];
  const float* W_value = (const float*)d_in[1];
  const float* b_value = (const float*)d_in[2];
  const float* W_off   = (const float*)d_in[3];
  const float* b_off   = (const float*)d_in[4];
  const float* W_attn  = (const float*)d_in[5];
  const float* b_attn  = (const float*)d_in[6];
  const float* W_out   = (const float*)d_in[7];
  const float* b_out   = (const float*)d_in[8];
  const float* W_proj  = (const float*)d_in[9];
  const float* b_proj  = (const float*)d_in[10];

  char* ws = (char*)d_ws;
  bf16*  x_bf    = (bf16*)(ws);                    // 29,360,128 B
  bf16*  y_bf    = x_bf;                           // alias (x dead after GEMM1)
  bf16*  C1      = (bf16*)(ws + 29360128);         // 36,700,160 B
  bf16*  Wcat_t  = (bf16*)(ws + 66060288);         //  2,621,440 B
  float* bcat    = (float*)(ws + 68681728);        //      5,120 B
  bf16*  Wout_b  = (bf16*)(ws + 68686848);         //  2,097,152 B
  bf16*  Wproj_t = (bf16*)(ws + 70784000);         //  2,097,152 B
  bf16*  Wc_t    = (bf16*)(ws + 72881152);         //  2,097,152 B
  float* bcomb   = (float*)(ws + 74978304);        //      4,096 B

  // -- 1: all conversions / transposes / biases / x->bf16 --
  k_prep_all<<<dim3(32, 137), 256, 0, stream>>>(
      x, W_value, W_off, W_attn, W_proj, W_out,
      b_value, b_off, b_attn, b_out, b_proj,
      x_bf, Wcat_t, Wproj_t, Wout_b, bcat, bcomb);

  // -- 2: GEMM1 (x@Wcat -> C1, 1120 blocks) + Wc = (Wout@Wproj)^T (64 blocks) --
  k_gemm_dual<1, 1><<<1120 + 64, 256, 0, stream>>>(
      x_bf, Wcat_t, C1, bcat, NCAT, DM, DM, DM, NCAT / 128, 1120,
      Wproj_t, Wout_b, Wc_t, nullptr, 1024, 1024, 1024, 1024, 8);

  // -- 3: deformable sampling + head combine -> y (bf16) --
  k_sample<<<ROWS / 8, 512, 0, stream>>>(C1, y_bf);

  // -- 4: final GEMM: y @ W_comb + b_comb -> out (fp32) --
  k_gemm_dual<0, 0><<<896, 256, 0, stream>>>(
      y_bf, Wc_t, (float*)d_out, bcomb, DM, DM, DM, DM, DM / 128, 896,
      y_bf, Wc_t, (float*)d_out, bcomb, DM, DM, DM, DM, DM / 128);
}

// Round 14
// 173.027 us; speedup vs baseline: 2.1915x; 2.1915x over previous
//
#include <hip/hip_runtime.h>
#include <hip/hip_bf16.h>

using bf16 = __hip_bfloat16;
typedef __attribute__((ext_vector_type(8))) short bf16x8;
typedef __attribute__((ext_vector_type(4))) float f32x4;

#define NB   1024
#define TT   14
#define DM   1024
#define ROWS (NB*TT)   // 14336
#define NCAT 1280      // 1216 padded to 10*128

__device__ __forceinline__ unsigned short f2b(float f) {
  union { bf16 h; unsigned short u; } cv; cv.h = __float2bfloat16(f); return cv.u;
}

__device__ __forceinline__ void gload16(const bf16* g, bf16* l) {
  __builtin_amdgcn_global_load_lds((const __attribute__((address_space(1))) void*)g,
                                   (__attribute__((address_space(3))) void*)l, 16, 0, 0);
}

// ---- one-shot prep: weight transposes + converts + biases + x->bf16 --------
__global__ __launch_bounds__(256) void k_prep_all(
    const float* __restrict__ x_in,
    const float* __restrict__ Wv, const float* __restrict__ Wo,
    const float* __restrict__ Wa, const float* __restrict__ Wproj,
    const float* __restrict__ Wout,
    const float* __restrict__ bv, const float* __restrict__ bo,
    const float* __restrict__ ba, const float* __restrict__ b_out,
    const float* __restrict__ b_proj,
    bf16* __restrict__ x_bf,
    bf16* __restrict__ wcat_t, bf16* __restrict__ wproj_t,
    bf16* __restrict__ wout_b, float* __restrict__ bcat,
    float* __restrict__ bcomb) {
  __shared__ float t[32][33];
  const int x = blockIdx.x, y = blockIdx.y;
  const int lx = threadIdx.x & 31, ly = threadIdx.x >> 5;
  if (y < 72) {
    const float* src; bf16* dst; int base, width;
    if (y < 40) {
      dst = wcat_t;
      int n0 = y * 32;
      if (n0 < 1024)      { src = Wv; base = 0;    width = 1024; }
      else if (n0 < 1152) { src = Wo; base = 1024; width = 128;  }
      else if (n0 < 1216) { src = Wa; base = 1152; width = 64;   }
      else                { src = nullptr; base = 0; width = 1;  }
      int k0 = x * 32, n0b = n0;
#pragma unroll
      for (int r = 0; r < 32; r += 8)
        t[ly + r][lx] = src ? src[(size_t)(k0 + ly + r) * width + (n0b - base + lx)] : 0.0f;
      __syncthreads();
#pragma unroll
      for (int r = 0; r < 32; r += 8)
        dst[(size_t)(n0b + ly + r) * 1024 + (k0 + lx)] = __float2bfloat16(t[lx][ly + r]);
    } else {
      int n0 = (y - 40) * 32, k0 = x * 32;
#pragma unroll
      for (int r = 0; r < 32; r += 8)
        t[ly + r][lx] = Wproj[(size_t)(k0 + ly + r) * 1024 + (n0 + lx)];
      __syncthreads();
#pragma unroll
      for (int r = 0; r < 32; r += 8)
        wproj_t[(size_t)(n0 + ly + r) * 1024 + (k0 + lx)] = __float2bfloat16(t[lx][ly + r]);
    }
  } else if (y < 80) {
    int i0 = ((y - 72) * 32 + x) * 1024 + threadIdx.x;
#pragma unroll
    for (int r = 0; r < 4; ++r) {
      int i = i0 + r * 256;
      float4 v = reinterpret_cast<const float4*>(Wout)[i];
      ushort4 o;
      o.x = f2b(v.x); o.y = f2b(v.y); o.z = f2b(v.z); o.w = f2b(v.w);
      reinterpret_cast<ushort4*>(wout_b)[i] = o;
    }
  } else if (y == 80) {
    if (x < 5) {
      int i = x * 256 + threadIdx.x;
      if (i < NCAT) {
        float v = 0.0f;
        if (i < 1024) v = bv[i];
        else if (i < 1152) v = bo[i - 1024];
        else if (i < 1216) v = ba[i - 1152];
        bcat[i] = v;
      }
    } else if (x < 21) {
      __shared__ float part[4][64];
      int j0 = (x - 5) * 64;
      int jl = threadIdx.x & 63, ip = threadIdx.x >> 6;
      int j = j0 + jl;
      float acc = 0.0f;
      int i0 = ip * 256;
      for (int i = i0; i < i0 + 256; ++i)
        acc = fmaf(b_out[i], Wproj[(size_t)i * 1024 + j], acc);
      part[ip][jl] = acc;
      __syncthreads();
      if (threadIdx.x < 64) {
        int jj = j0 + threadIdx.x;
        bcomb[jj] = part[0][threadIdx.x] + part[1][threadIdx.x] +
                    part[2][threadIdx.x] + part[3][threadIdx.x] + b_proj[jj];
      }
    }
  } else {
    int id = (y - 81) * 32 + x;
    int i0 = id * 2048 + threadIdx.x;
#pragma unroll
    for (int r = 0; r < 8; ++r) {
      int i = i0 + r * 256;
      float4 v = reinterpret_cast<const float4*>(x_in)[i];
      ushort4 o;
      o.x = f2b(v.x); o.y = f2b(v.y); o.z = f2b(v.z); o.w = f2b(v.w);
      reinterpret_cast<ushort4*>(x_bf)[i] = o;
    }
  }
}

// ------------------- dual-job bf16 MFMA GEMM (B^T), 128² tile ----------------
// 2-buffer/32KB variant of the measured-best structure with CORRECT launch
// bounds: __launch_bounds__(256,4) -> VGPR cap 128 (no spills; R12's (256,5)
// pinned VGPR to 48 and spilled 314MB of scratch), 4 blocks/CU (128KB LDS),
// 16 waves/CU.  Loop: {vmcnt(4); bar; COMPUTE(cur); bar; STAGE(cur, i+2)} —
// race-free (buffer overwritten only after all waves passed the 2nd barrier),
// counted vmcnt keeps 8 loads in flight.  Zero-conflict LDS pair (R11),
// swapped-operand MFMA, setprio, bijective XCD swizzle on job1.
template<int OUT1, int OUT2>
__global__ __launch_bounds__(256, 4) void k_gemm_dual(
    const bf16* __restrict__ A1, const bf16* __restrict__ B1,
    void* __restrict__ C1v, const float* __restrict__ bias1,
    int N1, int K1, int lda1, int ldb1, int nx1, int nwg1,
    const bf16* __restrict__ A2, const bf16* __restrict__ B2,
    void* __restrict__ C2v, const float* __restrict__ bias2,
    int N2, int K2, int lda2, int ldb2, int nx2) {
  constexpr int ASZ = 4096, BSZ = 4096;   // 128 rows x 32 k per buffer
  __shared__ bf16 As[2 * ASZ];
  __shared__ bf16 Bs[2 * BSZ];

  const int tid  = threadIdx.x;
  const int wave = tid >> 6, lane = tid & 63;

  const bf16 *A, *Bt; void* Cv; const float* bias;
  int N, K, lda, ldb, bx, by; bool ob;
  if ((int)blockIdx.x < nwg1) {
    int bid = blockIdx.x;
    int q = nwg1 >> 3, r = nwg1 & 7;
    int xcd = bid & 7, li = bid >> 3;
    bid = (xcd < r ? xcd * (q + 1) : r * (q + 1) + (xcd - r) * q) + li;
    A = A1; Bt = B1; Cv = C1v; bias = bias1;
    N = N1; K = K1; lda = lda1; ldb = ldb1;
    bx = bid % nx1; by = bid / nx1; ob = (OUT1 != 0);
  } else {
    int bid = blockIdx.x - nwg1;
    A = A2; Bt = B2; Cv = C2v; bias = bias2;
    N = N2; K = K2; lda = lda2; ldb = ldb2;
    bx = bid % nx2; by = bid / nx2; ob = (OUT2 != 0);
  }
  const int row0 = by * 128, col0 = bx * 128;
  const int wr = (wave >> 1) * 64, wc = (wave & 1) * 64;
  f32x4 acc[4][4] = {};

  // staging source: pre-swizzled slot so linear LDS dest == swizzled layout
  const int sr  = tid >> 2;
  const int scb = (tid & 3) ^ ((tid >> 3) & 3);
  const bf16* Ab = A  + (size_t)(row0 + sr) * lda + scb * 8;
  const bf16* Bb = Bt + (size_t)(col0 + sr) * ldb + scb * 8;

  // read offsets: lane-constant swizzled slot fs (zero-conflict pair, R11)
  const int fr = lane & 15, g = lane >> 4;
  const int fs = (g ^ ((fr >> 1) & 3)) * 8;
  int aoff[4], boff[4];
#pragma unroll
  for (int mi = 0; mi < 4; ++mi) {
    int row = wr + mi * 16 + fr, h = row >> 6, lr = row & 63;
    aoff[mi] = h * 2048 + lr * 32 + fs;
  }
#pragma unroll
  for (int ni = 0; ni < 4; ++ni) {
    int row = wc + ni * 16 + fr, h = row >> 6, lr = row & 63;
    boff[ni] = h * 2048 + lr * 32 + fs;
  }

  auto STAGE = [&](int s, int kk) {
    const int ko = kk * 32;
#pragma unroll
    for (int j = 0; j < 2; ++j)
      gload16(Ab + (size_t)j * 64 * lda + ko, As + s * ASZ + j * 2048 + tid * 8);
#pragma unroll
    for (int j = 0; j < 2; ++j)
      gload16(Bb + (size_t)j * 64 * ldb + ko, Bs + s * BSZ + j * 2048 + tid * 8);
  };
  auto COMPUTE = [&](int s) {
    const bf16* as = As + s * ASZ;
    const bf16* bs = Bs + s * BSZ;
    bf16x8 af[4], bfm[4];
#pragma unroll
    for (int mi = 0; mi < 4; ++mi) af[mi] = *(const bf16x8*)(as + aoff[mi]);
#pragma unroll
    for (int ni = 0; ni < 4; ++ni) bfm[ni] = *(const bf16x8*)(bs + boff[ni]);
    __builtin_amdgcn_s_setprio(1);
#pragma unroll
    for (int mi = 0; mi < 4; ++mi)
#pragma unroll
      for (int ni = 0; ni < 4; ++ni)   // swapped operands: acc holds C^T frag
        acc[mi][ni] = __builtin_amdgcn_mfma_f32_16x16x32_bf16(bfm[ni], af[mi], acc[mi][ni], 0, 0, 0);
    __builtin_amdgcn_s_setprio(0);
  };

  const int nk = K >> 5;
  STAGE(0, 0);
  STAGE(1, 1);
  int cur = 0;
  for (int i = 0; i < nk; ++i) {
    // ledger: outstanding = tiles {i, i+1} (8 loads); vmcnt(4) drains tile i
    if (i < nk - 1) asm volatile("s_waitcnt vmcnt(4)" ::: "memory");
    else            asm volatile("s_waitcnt vmcnt(0)" ::: "memory");
    __builtin_amdgcn_s_barrier();
    asm volatile("" ::: "memory");
    COMPUTE(cur);
    __builtin_amdgcn_s_barrier();          // all waves done reading buf cur
    asm volatile("" ::: "memory");
    if (i + 2 < nk) STAGE(cur, i + 2);     // overwrite just-freed buffer
    cur ^= 1;
  }

  // epilogue: thread holds row gr, 4 consecutive cols per fragment
  const int fq = g * 4;
#pragma unroll
  for (int mi = 0; mi < 4; ++mi) {
    int gr = row0 + wr + mi * 16 + fr;
#pragma unroll
    for (int ni = 0; ni < 4; ++ni) {
      int gc = col0 + wc + ni * 16 + fq;
      float b0 = 0, b1 = 0, b2 = 0, b3 = 0;
      if (bias) {
        float4 bv = *reinterpret_cast<const float4*>(bias + gc);
        b0 = bv.x; b1 = bv.y; b2 = bv.z; b3 = bv.w;
      }
      float v0 = acc[mi][ni][0] + b0, v1 = acc[mi][ni][1] + b1;
      float v2 = acc[mi][ni][2] + b2, v3 = acc[mi][ni][3] + b3;
      if (ob) {
        ushort4 u; u.x = f2b(v0); u.y = f2b(v1); u.z = f2b(v2); u.w = f2b(v3);
        *reinterpret_cast<ushort4*>((bf16*)Cv + (size_t)gr * N + gc) = u;
      } else {
        float4 o; o.x = v0; o.y = v1; o.z = v2; o.w = v3;
        *reinterpret_cast<float4*>((float*)Cv + (size_t)gr * N + gc) = o;
      }
    }
  }
}

// ------------------------------- sampling -----------------------------------
// C1: [ROWS][1280] bf16 = [value(1024) | off(128) | attn(64) | pad(64)] (+bias).
__global__ __launch_bounds__(512) void k_sample(const bf16* __restrict__ C1,
                                                bf16* __restrict__ y) {
  const int wave = threadIdx.x >> 6, lane = threadIdx.x & 63;
  const int row = blockIdx.x * 8 + wave;           // < 14336
  const int b = row / TT, t = row - b * TT;
  const bf16* r1 = C1 + (size_t)row * NCAT;

  float offx, offy;
  {
    ushort2 u = *reinterpret_cast<const ushort2*>(r1 + 1024 + lane * 2);
    offx = __uint_as_float(((unsigned)u.x) << 16);
    offy = __uint_as_float(((unsigned)u.y) << 16);
  }
  float logit;
  {
    unsigned short u = reinterpret_cast<const unsigned short*>(r1)[1152 + lane];
    logit = __uint_as_float(((unsigned)u) << 16);
  }
  float m = fmaxf(logit, __shfl_xor(logit, 1));
  m = fmaxf(m, __shfl_xor(m, 2));
  float e = __expf(logit - m);
  float s = e + __shfl_xor(e, 1);
  s = s + __shfl_xor(s, 2);
  float aw = e / s;

  const float refx = (float)t * (1.0f / 13.0f);
  float ix = refx + offx - 0.5f;
  float xf = floorf(ix);
  float fx = ix - xf;
  float wx = (xf == 0.0f) ? (1.0f - fx) : ((xf == -1.0f) ? fx : 0.0f);

  float iy = offy - 0.5f;
  float yf = floorf(iy);
  float fy = iy - yf;
  int y0 = (int)yf, y1 = y0 + 1;
  float w0 = (y0 >= 0 && y0 < TT) ? (1.0f - fy) : 0.0f;
  float w1 = (y1 >= 0 && y1 < TT) ? fy : 0.0f;
  int i0 = max(0, min(TT - 1, y0));
  int i1 = max(0, min(TT - 1, y1));
  float cw0 = aw * wx * w0;
  float cw1 = aw * wx * w1;

  const bf16* vb = C1 + (size_t)(b * TT) * NCAT;
  float acc[16];
#pragma unroll
  for (int h = 0; h < 16; ++h) acc[h] = 0.0f;
#pragma unroll
  for (int j = 0; j < 64; ++j) {
    float c0 = __shfl(cw0, j);
    float c1 = __shfl(cw1, j);
    int a0 = __shfl(i0, j);
    int a1 = __shfl(i1, j);
    const int hh = j >> 2;
    float v0 = __bfloat162float(vb[(size_t)a0 * NCAT + hh * 64 + lane]);
    float v1 = __bfloat162float(vb[(size_t)a1 * NCAT + hh * 64 + lane]);
    acc[hh] = fmaf(c0, v0, fmaf(c1, v1, acc[hh]));
  }
#pragma unroll
  for (int h = 0; h < 16; ++h)
    y[(size_t)row * DM + h * 64 + lane] = __float2bfloat16(acc[h]);
}

// ------------------------------- launcher -----------------------------------
extern "C" void kernel_launch(void* const* d_in, const int* in_sizes, int n_in,
                              void* d_out, int out_size, void* d_ws, size_t ws_size,
                              hipStream_t stream) {
  (void)in_sizes; (void)n_in; (void)out_size; (void)ws_size;
  const float* x       = (const float*)d_in[0];
  const float* W_value = (const float*)d_in[1];
  const float* b_value = (const float*)d_in[2];
  const float* W_off   = (const float*)d_in[3];
  const float* b_off   = (const float*)d_in[4];
  const float* W_attn  = (const float*)d_in[5];
  const float* b_attn  = (const float*)d_in[6];
  const float* W_out   = (const float*)d_in[7];
  const float* b_out   = (const float*)d_in[8];
  const float* W_proj  = (const float*)d_in[9];
  const float* b_proj  = (const float*)d_in[10];

  char* ws = (char*)d_ws;
  bf16*  x_bf    = (bf16*)(ws);                    // 29,360,128 B
  bf16*  y_bf    = x_bf;                           // alias (x dead after GEMM1)
  bf16*  C1      = (bf16*)(ws + 29360128);         // 36,700,160 B
  bf16*  Wcat_t  = (bf16*)(ws + 66060288);         //  2,621,440 B
  float* bcat    = (float*)(ws + 68681728);        //      5,120 B
  bf16*  Wout_b  = (bf16*)(ws + 68686848);         //  2,097,152 B
  bf16*  Wproj_t = (bf16*)(ws + 70784000);         //  2,097,152 B
  bf16*  Wc_t    = (bf16*)(ws + 72881152);         //  2,097,152 B
  float* bcomb   = (float*)(ws + 74978304);        //      4,096 B

  // -- 1: all conversions / transposes / biases / x->bf16 --
  k_prep_all<<<dim3(32, 137), 256, 0, stream>>>(
      x, W_value, W_off, W_attn, W_proj, W_out,
      b_value, b_off, b_attn, b_out, b_proj,
      x_bf, Wcat_t, Wproj_t, Wout_b, bcat, bcomb);

  // -- 2: GEMM1 (x@Wcat -> C1, 1120 blocks) + Wc = (Wout@Wproj)^T (64 blocks) --
  k_gemm_dual<1, 1><<<1120 + 64, 256, 0, stream>>>(
      x_bf, Wcat_t, C1, bcat, NCAT, DM, DM, DM, NCAT / 128, 1120,
      Wproj_t, Wout_b, Wc_t, nullptr, 1024, 1024, 1024, 1024, 8);

  // -- 3: deformable sampling + head combine -> y (bf16) --
  k_sample<<<ROWS / 8, 512, 0, stream>>>(C1, y_bf);

  // -- 4: final GEMM: y @ W_comb + b_comb -> out (fp32) --
  k_gemm_dual<0, 0><<<896, 256, 0, stream>>>(
      y_bf, Wc_t, (float*)d_out, bcomb, DM, DM, DM, DM, DM / 128, 896,
      y_bf, Wc_t, (float*)d_out, bcomb, DM, DM, DM, DM, DM / 128);
}

// Round 15
// 156.545 us; speedup vs baseline: 2.4222x; 1.1053x over previous
//
#include <hip/hip_runtime.h>
#include <hip/hip_bf16.h>

using bf16 = __hip_bfloat16;
typedef __attribute__((ext_vector_type(8))) short bf16x8;
typedef __attribute__((ext_vector_type(4))) float f32x4;

#define NB   1024
#define TT   14
#define DM   1024
#define ROWS (NB*TT)   // 14336
#define NCAT 1280      // 1216 padded to 10*128

__device__ __forceinline__ unsigned short f2b(float f) {
  union { bf16 h; unsigned short u; } cv; cv.h = __float2bfloat16(f); return cv.u;
}

__device__ __forceinline__ void gload16(const bf16* g, bf16* l) {
  __builtin_amdgcn_global_load_lds((const __attribute__((address_space(1))) void*)g,
                                   (__attribute__((address_space(3))) void*)l, 16, 0, 0);
}

// ---- one-shot prep: weight transposes + converts + biases + x->bf16 --------
__global__ __launch_bounds__(256) void k_prep_all(
    const float* __restrict__ x_in,
    const float* __restrict__ Wv, const float* __restrict__ Wo,
    const float* __restrict__ Wa, const float* __restrict__ Wproj,
    const float* __restrict__ Wout,
    const float* __restrict__ bv, const float* __restrict__ bo,
    const float* __restrict__ ba, const float* __restrict__ b_out,
    const float* __restrict__ b_proj,
    bf16* __restrict__ x_bf,
    bf16* __restrict__ wcat_t, bf16* __restrict__ wproj_t,
    bf16* __restrict__ wout_b, float* __restrict__ bcat,
    float* __restrict__ bcomb) {
  __shared__ float t[32][33];
  const int x = blockIdx.x, y = blockIdx.y;
  const int lx = threadIdx.x & 31, ly = threadIdx.x >> 5;
  if (y < 72) {
    const float* src; bf16* dst; int base, width;
    if (y < 40) {
      dst = wcat_t;
      int n0 = y * 32;
      if (n0 < 1024)      { src = Wv; base = 0;    width = 1024; }
      else if (n0 < 1152) { src = Wo; base = 1024; width = 128;  }
      else if (n0 < 1216) { src = Wa; base = 1152; width = 64;   }
      else                { src = nullptr; base = 0; width = 1;  }
      int k0 = x * 32, n0b = n0;
#pragma unroll
      for (int r = 0; r < 32; r += 8)
        t[ly + r][lx] = src ? src[(size_t)(k0 + ly + r) * width + (n0b - base + lx)] : 0.0f;
      __syncthreads();
#pragma unroll
      for (int r = 0; r < 32; r += 8)
        dst[(size_t)(n0b + ly + r) * 1024 + (k0 + lx)] = __float2bfloat16(t[lx][ly + r]);
    } else {
      int n0 = (y - 40) * 32, k0 = x * 32;
#pragma unroll
      for (int r = 0; r < 32; r += 8)
        t[ly + r][lx] = Wproj[(size_t)(k0 + ly + r) * 1024 + (n0 + lx)];
      __syncthreads();
#pragma unroll
      for (int r = 0; r < 32; r += 8)
        wproj_t[(size_t)(n0 + ly + r) * 1024 + (k0 + lx)] = __float2bfloat16(t[lx][ly + r]);
    }
  } else if (y < 80) {
    int i0 = ((y - 72) * 32 + x) * 1024 + threadIdx.x;
#pragma unroll
    for (int r = 0; r < 4; ++r) {
      int i = i0 + r * 256;
      float4 v = reinterpret_cast<const float4*>(Wout)[i];
      ushort4 o;
      o.x = f2b(v.x); o.y = f2b(v.y); o.z = f2b(v.z); o.w = f2b(v.w);
      reinterpret_cast<ushort4*>(wout_b)[i] = o;
    }
  } else if (y == 80) {
    if (x < 5) {
      int i = x * 256 + threadIdx.x;
      if (i < NCAT) {
        float v = 0.0f;
        if (i < 1024) v = bv[i];
        else if (i < 1152) v = bo[i - 1024];
        else if (i < 1216) v = ba[i - 1152];
        bcat[i] = v;
      }
    } else if (x < 21) {
      __shared__ float part[4][64];
      int j0 = (x - 5) * 64;
      int jl = threadIdx.x & 63, ip = threadIdx.x >> 6;
      int j = j0 + jl;
      float acc = 0.0f;
      int i0 = ip * 256;
      for (int i = i0; i < i0 + 256; ++i)
        acc = fmaf(b_out[i], Wproj[(size_t)i * 1024 + j], acc);
      part[ip][jl] = acc;
      __syncthreads();
      if (threadIdx.x < 64) {
        int jj = j0 + threadIdx.x;
        bcomb[jj] = part[0][threadIdx.x] + part[1][threadIdx.x] +
                    part[2][threadIdx.x] + part[3][threadIdx.x] + b_proj[jj];
      }
    }
  } else {
    int id = (y - 81) * 32 + x;
    int i0 = id * 2048 + threadIdx.x;
#pragma unroll
    for (int r = 0; r < 8; ++r) {
      int i = i0 + r * 256;
      float4 v = reinterpret_cast<const float4*>(x_in)[i];
      ushort4 o;
      o.x = f2b(v.x); o.y = f2b(v.y); o.z = f2b(v.z); o.w = f2b(v.w);
      reinterpret_cast<ushort4*>(x_bf)[i] = o;
    }
  }
}

// ------------------- dual-job bf16 MFMA GEMM (B^T), 128² tile ----------------
// Measured-best family floor (R13): double-buffered 32KB LDS, counted vmcnt(4)
// (loads span barriers), loop {vmcnt; bar; COMPUTE(cur); bar; STAGE(cur,i+2)},
// zero-conflict LDS addressing pair (R11), swapped-operand MFMA -> 4-col
// vector stores, setprio, bijective XCD swizzle on job1.  (256,4) bounds:
// VGPR 56, no spill; HW co-schedules up to 5 blocks/CU.
template<int OUT1, int OUT2>
__global__ __launch_bounds__(256, 4) void k_gemm_dual(
    const bf16* __restrict__ A1, const bf16* __restrict__ B1,
    void* __restrict__ C1v, const float* __restrict__ bias1,
    int N1, int K1, int lda1, int ldb1, int nx1, int nwg1,
    const bf16* __restrict__ A2, const bf16* __restrict__ B2,
    void* __restrict__ C2v, const float* __restrict__ bias2,
    int N2, int K2, int lda2, int ldb2, int nx2) {
  constexpr int ASZ = 4096, BSZ = 4096;   // 128 rows x 32 k per buffer
  __shared__ bf16 As[2 * ASZ];
  __shared__ bf16 Bs[2 * BSZ];

  const int tid  = threadIdx.x;
  const int wave = tid >> 6, lane = tid & 63;

  const bf16 *A, *Bt; void* Cv; const float* bias;
  int N, K, lda, ldb, bx, by; bool ob;
  if ((int)blockIdx.x < nwg1) {
    int bid = blockIdx.x;
    int q = nwg1 >> 3, r = nwg1 & 7;
    int xcd = bid & 7, li = bid >> 3;
    bid = (xcd < r ? xcd * (q + 1) : r * (q + 1) + (xcd - r) * q) + li;
    A = A1; Bt = B1; Cv = C1v; bias = bias1;
    N = N1; K = K1; lda = lda1; ldb = ldb1;
    bx = bid % nx1; by = bid / nx1; ob = (OUT1 != 0);
  } else {
    int bid = blockIdx.x - nwg1;
    A = A2; Bt = B2; Cv = C2v; bias = bias2;
    N = N2; K = K2; lda = lda2; ldb = ldb2;
    bx = bid % nx2; by = bid / nx2; ob = (OUT2 != 0);
  }
  const int row0 = by * 128, col0 = bx * 128;
  const int wr = (wave >> 1) * 64, wc = (wave & 1) * 64;
  f32x4 acc[4][4] = {};

  // staging source: pre-swizzled slot so linear LDS dest == swizzled layout
  const int sr  = tid >> 2;
  const int scb = (tid & 3) ^ ((tid >> 3) & 3);
  const bf16* Ab = A  + (size_t)(row0 + sr) * lda + scb * 8;
  const bf16* Bb = Bt + (size_t)(col0 + sr) * ldb + scb * 8;

  // read offsets: lane-constant swizzled slot fs (zero-conflict pair, R11)
  const int fr = lane & 15, g = lane >> 4;
  const int fs = (g ^ ((fr >> 1) & 3)) * 8;
  int aoff[4], boff[4];
#pragma unroll
  for (int mi = 0; mi < 4; ++mi) {
    int row = wr + mi * 16 + fr, h = row >> 6, lr = row & 63;
    aoff[mi] = h * 2048 + lr * 32 + fs;
  }
#pragma unroll
  for (int ni = 0; ni < 4; ++ni) {
    int row = wc + ni * 16 + fr, h = row >> 6, lr = row & 63;
    boff[ni] = h * 2048 + lr * 32 + fs;
  }

  auto STAGE = [&](int s, int kk) {
    const int ko = kk * 32;
#pragma unroll
    for (int j = 0; j < 2; ++j)
      gload16(Ab + (size_t)j * 64 * lda + ko, As + s * ASZ + j * 2048 + tid * 8);
#pragma unroll
    for (int j = 0; j < 2; ++j)
      gload16(Bb + (size_t)j * 64 * ldb + ko, Bs + s * BSZ + j * 2048 + tid * 8);
  };
  auto COMPUTE = [&](int s) {
    const bf16* as = As + s * ASZ;
    const bf16* bs = Bs + s * BSZ;
    bf16x8 af[4], bfm[4];
#pragma unroll
    for (int mi = 0; mi < 4; ++mi) af[mi] = *(const bf16x8*)(as + aoff[mi]);
#pragma unroll
    for (int ni = 0; ni < 4; ++ni) bfm[ni] = *(const bf16x8*)(bs + boff[ni]);
    __builtin_amdgcn_s_setprio(1);
#pragma unroll
    for (int mi = 0; mi < 4; ++mi)
#pragma unroll
      for (int ni = 0; ni < 4; ++ni)   // swapped operands: acc holds C^T frag
        acc[mi][ni] = __builtin_amdgcn_mfma_f32_16x16x32_bf16(bfm[ni], af[mi], acc[mi][ni], 0, 0, 0);
    __builtin_amdgcn_s_setprio(0);
  };

  const int nk = K >> 5;
  STAGE(0, 0);
  STAGE(1, 1);
  int cur = 0;
  for (int i = 0; i < nk; ++i) {
    // ledger: outstanding = tiles {i, i+1} (8 loads); vmcnt(4) drains tile i
    if (i < nk - 1) asm volatile("s_waitcnt vmcnt(4)" ::: "memory");
    else            asm volatile("s_waitcnt vmcnt(0)" ::: "memory");
    __builtin_amdgcn_s_barrier();
    asm volatile("" ::: "memory");
    COMPUTE(cur);
    __builtin_amdgcn_s_barrier();          // all waves done reading buf cur
    asm volatile("" ::: "memory");
    if (i + 2 < nk) STAGE(cur, i + 2);     // overwrite just-freed buffer
    cur ^= 1;
  }

  // epilogue: thread holds row gr, 4 consecutive cols per fragment
  const int fq = g * 4;
#pragma unroll
  for (int mi = 0; mi < 4; ++mi) {
    int gr = row0 + wr + mi * 16 + fr;
#pragma unroll
    for (int ni = 0; ni < 4; ++ni) {
      int gc = col0 + wc + ni * 16 + fq;
      float b0 = 0, b1 = 0, b2 = 0, b3 = 0;
      if (bias) {
        float4 bv = *reinterpret_cast<const float4*>(bias + gc);
        b0 = bv.x; b1 = bv.y; b2 = bv.z; b3 = bv.w;
      }
      float v0 = acc[mi][ni][0] + b0, v1 = acc[mi][ni][1] + b1;
      float v2 = acc[mi][ni][2] + b2, v3 = acc[mi][ni][3] + b3;
      if (ob) {
        ushort4 u; u.x = f2b(v0); u.y = f2b(v1); u.z = f2b(v2); u.w = f2b(v3);
        *reinterpret_cast<ushort4*>((bf16*)Cv + (size_t)gr * N + gc) = u;
      } else {
        float4 o; o.x = v0; o.y = v1; o.z = v2; o.w = v3;
        *reinterpret_cast<float4*>((float*)Cv + (size_t)gr * N + gc) = o;
      }
    }
  }
}

// ------------------------------- sampling -----------------------------------
// C1: [ROWS][1280] bf16 = [value(1024) | off(128) | attn(64) | pad(64)] (+bias).
// One wave per (b,t) row; 8 waves/block.  Weight phase: lane l owns
// (h,p) = (l>>2, l&3).  Gather phase (2-head-wide): iter j in [0,32):
// p = j&3, hbase = j>>2; lanes 0-31 handle head hbase, lanes 32-63 head
// hbase+8; each lane loads ushort2 = 2 channels (lane&31)*2, +1.  Weight
// shuffle source = j + (lane & 32)  (== h*4+p for that half's head).
__global__ __launch_bounds__(512) void k_sample(const bf16* __restrict__ C1,
                                                bf16* __restrict__ y) {
  const int wave = threadIdx.x >> 6, lane = threadIdx.x & 63;
  const int row = blockIdx.x * 8 + wave;           // < 14336
  const int b = row / TT, t = row - b * TT;
  const bf16* r1 = C1 + (size_t)row * NCAT;

  float offx, offy;
  {
    ushort2 u = *reinterpret_cast<const ushort2*>(r1 + 1024 + lane * 2);
    offx = __uint_as_float(((unsigned)u.x) << 16);
    offy = __uint_as_float(((unsigned)u.y) << 16);
  }
  float logit;
  {
    unsigned short u = reinterpret_cast<const unsigned short*>(r1)[1152 + lane];
    logit = __uint_as_float(((unsigned)u) << 16);
  }
  float m = fmaxf(logit, __shfl_xor(logit, 1));
  m = fmaxf(m, __shfl_xor(m, 2));
  float e = __expf(logit - m);
  float s = e + __shfl_xor(e, 1);
  s = s + __shfl_xor(s, 2);
  float aw = e / s;

  const float refx = (float)t * (1.0f / 13.0f);
  float ix = refx + offx - 0.5f;
  float xf = floorf(ix);
  float fx = ix - xf;
  float wx = (xf == 0.0f) ? (1.0f - fx) : ((xf == -1.0f) ? fx : 0.0f);

  float iy = offy - 0.5f;
  float yf = floorf(iy);
  float fy = iy - yf;
  int y0 = (int)yf, y1 = y0 + 1;
  float w0 = (y0 >= 0 && y0 < TT) ? (1.0f - fy) : 0.0f;
  float w1 = (y1 >= 0 && y1 < TT) ? fy : 0.0f;
  int i0 = max(0, min(TT - 1, y0));
  int i1 = max(0, min(TT - 1, y1));
  float cw0 = aw * wx * w0;
  float cw1 = aw * wx * w1;

  // ---- 2-head-wide gather: 32 iters, ushort2 loads ----
  const bf16* vb = C1 + (size_t)(b * TT) * NCAT;
  const int hofs = (lane & 32) ? 8 : 0;       // head offset for this half
  const int cofs = (lane & 31) * 2;           // channel pair within head
  float acc0[8], acc1[8];                     // heads hbase(+8), ch {c, c+1}
#pragma unroll
  for (int h = 0; h < 8; ++h) { acc0[h] = 0.0f; acc1[h] = 0.0f; }
#pragma unroll
  for (int j = 0; j < 32; ++j) {
    const int src = j + (lane & 32);          // weight lane = h*4 + p
    float c0 = __shfl(cw0, src);
    float c1 = __shfl(cw1, src);
    int a0 = __shfl(i0, src);
    int a1 = __shfl(i1, src);
    const int hb = j >> 2;
    const int ho = (hb + hofs) * 64 + cofs;
    ushort2 u0 = *reinterpret_cast<const ushort2*>(
        reinterpret_cast<const unsigned short*>(vb) + (size_t)a0 * NCAT + ho);
    ushort2 u1 = *reinterpret_cast<const ushort2*>(
        reinterpret_cast<const unsigned short*>(vb) + (size_t)a1 * NCAT + ho);
    float v00 = __uint_as_float(((unsigned)u0.x) << 16);
    float v01 = __uint_as_float(((unsigned)u0.y) << 16);
    float v10 = __uint_as_float(((unsigned)u1.x) << 16);
    float v11 = __uint_as_float(((unsigned)u1.y) << 16);
    acc0[hb] = fmaf(c0, v00, fmaf(c1, v10, acc0[hb]));
    acc1[hb] = fmaf(c0, v01, fmaf(c1, v11, acc1[hb]));
  }
#pragma unroll
  for (int hb = 0; hb < 8; ++hb) {
    ushort2 o;
    o.x = f2b(acc0[hb]);
    o.y = f2b(acc1[hb]);
    *reinterpret_cast<ushort2*>(
        reinterpret_cast<unsigned short*>(y) +
        (size_t)row * DM + (hb + hofs) * 64 + cofs) = o;
  }
}

// ------------------------------- launcher -----------------------------------
extern "C" void kernel_launch(void* const* d_in, const int* in_sizes, int n_in,
                              void* d_out, int out_size, void* d_ws, size_t ws_size,
                              hipStream_t stream) {
  (void)in_sizes; (void)n_in; (void)out_size; (void)ws_size;
  const float* x       = (const float*)d_in[0];
  const float* W_value = (const float*)d_in[1];
  const float* b_value = (const float*)d_in[2];
  const float* W_off   = (const float*)d_in[3];
  const float* b_off   = (const float*)d_in[4];
  const float* W_attn  = (const float*)d_in[5];
  const float* b_attn  = (const float*)d_in[6];
  const float* W_out   = (const float*)d_in[7];
  const float* b_out   = (const float*)d_in[8];
  const float* W_proj  = (const float*)d_in[9];
  const float* b_proj  = (const float*)d_in[10];

  char* ws = (char*)d_ws;
  bf16*  x_bf    = (bf16*)(ws);                    // 29,360,128 B
  bf16*  y_bf    = x_bf;                           // alias (x dead after GEMM1)
  bf16*  C1      = (bf16*)(ws + 29360128);         // 36,700,160 B
  bf16*  Wcat_t  = (bf16*)(ws + 66060288);         //  2,621,440 B
  float* bcat    = (float*)(ws + 68681728);        //      5,120 B
  bf16*  Wout_b  = (bf16*)(ws + 68686848);         //  2,097,152 B
  bf16*  Wproj_t = (bf16*)(ws + 70784000);         //  2,097,152 B
  bf16*  Wc_t    = (bf16*)(ws + 72881152);         //  2,097,152 B
  float* bcomb   = (float*)(ws + 74978304);        //      4,096 B

  // -- 1: all conversions / transposes / biases / x->bf16 --
  k_prep_all<<<dim3(32, 137), 256, 0, stream>>>(
      x, W_value, W_off, W_attn, W_proj, W_out,
      b_value, b_off, b_attn, b_out, b_proj,
      x_bf, Wcat_t, Wproj_t, Wout_b, bcat, bcomb);

  // -- 2: GEMM1 (x@Wcat -> C1, 1120 blocks) + Wc = (Wout@Wproj)^T (64 blocks) --
  k_gemm_dual<1, 1><<<1120 + 64, 256, 0, stream>>>(
      x_bf, Wcat_t, C1, bcat, NCAT, DM, DM, DM, NCAT / 128, 1120,
      Wproj_t, Wout_b, Wc_t, nullptr, 1024, 1024, 1024, 1024, 8);

  // -- 3: deformable sampling + head combine -> y (bf16) --
  k_sample<<<ROWS / 8, 512, 0, stream>>>(C1, y_bf);

  // -- 4: final GEMM: y @ W_comb + b_comb -> out (fp32) --
  k_gemm_dual<0, 0><<<896, 256, 0, stream>>>(
      y_bf, Wc_t, (float*)d_out, bcomb, DM, DM, DM, DM, DM / 128, 896,
      y_bf, Wc_t, (float*)d_out, bcomb, DM, DM, DM, DM, DM / 128);
}

// Round 16
// 156.417 us; speedup vs baseline: 2.4242x; 1.0008x over previous
//
#include <hip/hip_runtime.h>
#include <hip/hip_bf16.h>

using bf16 = __hip_bfloat16;
typedef __attribute__((ext_vector_type(8))) short bf16x8;
typedef __attribute__((ext_vector_type(4))) float f32x4;

#define NB   1024
#define TT   14
#define DM   1024
#define ROWS (NB*TT)   // 14336
#define NCAT 1280      // 1216 padded to 10*128

__device__ __forceinline__ unsigned short f2b(float f) {
  union { bf16 h; unsigned short u; } cv; cv.h = __float2bfloat16(f); return cv.u;
}

__device__ __forceinline__ void gload16(const bf16* g, bf16* l) {
  __builtin_amdgcn_global_load_lds((const __attribute__((address_space(1))) void*)g,
                                   (__attribute__((address_space(3))) void*)l, 16, 0, 0);
}

// ---- one-shot prep: weight transposes + converts + biases + x->bf16 --------
__global__ __launch_bounds__(256) void k_prep_all(
    const float* __restrict__ x_in,
    const float* __restrict__ Wv, const float* __restrict__ Wo,
    const float* __restrict__ Wa, const float* __restrict__ Wproj,
    const float* __restrict__ Wout,
    const float* __restrict__ bv, const float* __restrict__ bo,
    const float* __restrict__ ba, const float* __restrict__ b_out,
    const float* __restrict__ b_proj,
    bf16* __restrict__ x_bf,
    bf16* __restrict__ wcat_t, bf16* __restrict__ wproj_t,
    bf16* __restrict__ wout_b, float* __restrict__ bcat,
    float* __restrict__ bcomb) {
  __shared__ float t[32][33];
  const int x = blockIdx.x, y = blockIdx.y;
  const int lx = threadIdx.x & 31, ly = threadIdx.x >> 5;
  if (y < 72) {
    const float* src; bf16* dst; int base, width;
    if (y < 40) {
      dst = wcat_t;
      int n0 = y * 32;
      if (n0 < 1024)      { src = Wv; base = 0;    width = 1024; }
      else if (n0 < 1152) { src = Wo; base = 1024; width = 128;  }
      else if (n0 < 1216) { src = Wa; base = 1152; width = 64;   }
      else                { src = nullptr; base = 0; width = 1;  }
      int k0 = x * 32, n0b = n0;
#pragma unroll
      for (int r = 0; r < 32; r += 8)
        t[ly + r][lx] = src ? src[(size_t)(k0 + ly + r) * width + (n0b - base + lx)] : 0.0f;
      __syncthreads();
#pragma unroll
      for (int r = 0; r < 32; r += 8)
        dst[(size_t)(n0b + ly + r) * 1024 + (k0 + lx)] = __float2bfloat16(t[lx][ly + r]);
    } else {
      int n0 = (y - 40) * 32, k0 = x * 32;
#pragma unroll
      for (int r = 0; r < 32; r += 8)
        t[ly + r][lx] = Wproj[(size_t)(k0 + ly + r) * 1024 + (n0 + lx)];
      __syncthreads();
#pragma unroll
      for (int r = 0; r < 32; r += 8)
        wproj_t[(size_t)(n0 + ly + r) * 1024 + (k0 + lx)] = __float2bfloat16(t[lx][ly + r]);
    }
  } else if (y < 80) {
    int i0 = ((y - 72) * 32 + x) * 1024 + threadIdx.x;
#pragma unroll
    for (int r = 0; r < 4; ++r) {
      int i = i0 + r * 256;
      float4 v = reinterpret_cast<const float4*>(Wout)[i];
      ushort4 o;
      o.x = f2b(v.x); o.y = f2b(v.y); o.z = f2b(v.z); o.w = f2b(v.w);
      reinterpret_cast<ushort4*>(wout_b)[i] = o;
    }
  } else if (y == 80) {
    if (x < 5) {
      int i = x * 256 + threadIdx.x;
      if (i < NCAT) {
        float v = 0.0f;
        if (i < 1024) v = bv[i];
        else if (i < 1152) v = bo[i - 1024];
        else if (i < 1216) v = ba[i - 1152];
        bcat[i] = v;
      }
    } else if (x < 21) {
      __shared__ float part[4][64];
      int j0 = (x - 5) * 64;
      int jl = threadIdx.x & 63, ip = threadIdx.x >> 6;
      int j = j0 + jl;
      float acc = 0.0f;
      int i0 = ip * 256;
      for (int i = i0; i < i0 + 256; ++i)
        acc = fmaf(b_out[i], Wproj[(size_t)i * 1024 + j], acc);
      part[ip][jl] = acc;
      __syncthreads();
      if (threadIdx.x < 64) {
        int jj = j0 + threadIdx.x;
        bcomb[jj] = part[0][threadIdx.x] + part[1][threadIdx.x] +
                    part[2][threadIdx.x] + part[3][threadIdx.x] + b_proj[jj];
      }
    }
  } else {
    int id = (y - 81) * 32 + x;
    int i0 = id * 2048 + threadIdx.x;
#pragma unroll
    for (int r = 0; r < 8; ++r) {
      int i = i0 + r * 256;
      float4 v = reinterpret_cast<const float4*>(x_in)[i];
      ushort4 o;
      o.x = f2b(v.x); o.y = f2b(v.y); o.z = f2b(v.z); o.w = f2b(v.w);
      reinterpret_cast<ushort4*>(x_bf)[i] = o;
    }
  }
}

// ------------------- dual-job bf16 MFMA GEMM (B^T), 128² tile ----------------
// Proven R13 structure (control): 2-buf 32KB LDS, counted vmcnt(4), loop
// {vmcnt; bar; COMPUTE; bar; STAGE(cur,i+2)}, zero-conflict LDS pair,
// swapped-operand MFMA, setprio, bijective XCD swizzle on job1.
template<int OUT1, int OUT2>
__global__ __launch_bounds__(256, 4) void k_gemm_dual(
    const bf16* __restrict__ A1, const bf16* __restrict__ B1,
    void* __restrict__ C1v, const float* __restrict__ bias1,
    int N1, int K1, int lda1, int ldb1, int nx1, int nwg1,
    const bf16* __restrict__ A2, const bf16* __restrict__ B2,
    void* __restrict__ C2v, const float* __restrict__ bias2,
    int N2, int K2, int lda2, int ldb2, int nx2) {
  constexpr int ASZ = 4096, BSZ = 4096;
  __shared__ bf16 As[2 * ASZ];
  __shared__ bf16 Bs[2 * BSZ];

  const int tid  = threadIdx.x;
  const int wave = tid >> 6, lane = tid & 63;

  const bf16 *A, *Bt; void* Cv; const float* bias;
  int N, K, lda, ldb, bx, by; bool ob;
  if ((int)blockIdx.x < nwg1) {
    int bid = blockIdx.x;
    int q = nwg1 >> 3, r = nwg1 & 7;
    int xcd = bid & 7, li = bid >> 3;
    bid = (xcd < r ? xcd * (q + 1) : r * (q + 1) + (xcd - r) * q) + li;
    A = A1; Bt = B1; Cv = C1v; bias = bias1;
    N = N1; K = K1; lda = lda1; ldb = ldb1;
    bx = bid % nx1; by = bid / nx1; ob = (OUT1 != 0);
  } else {
    int bid = blockIdx.x - nwg1;
    A = A2; Bt = B2; Cv = C2v; bias = bias2;
    N = N2; K = K2; lda = lda2; ldb = ldb2;
    bx = bid % nx2; by = bid / nx2; ob = (OUT2 != 0);
  }
  const int row0 = by * 128, col0 = bx * 128;
  const int wr = (wave >> 1) * 64, wc = (wave & 1) * 64;
  f32x4 acc[4][4] = {};

  const int sr  = tid >> 2;
  const int scb = (tid & 3) ^ ((tid >> 3) & 3);
  const bf16* Ab = A  + (size_t)(row0 + sr) * lda + scb * 8;
  const bf16* Bb = Bt + (size_t)(col0 + sr) * ldb + scb * 8;

  const int fr = lane & 15, g = lane >> 4;
  const int fs = (g ^ ((fr >> 1) & 3)) * 8;
  int aoff[4], boff[4];
#pragma unroll
  for (int mi = 0; mi < 4; ++mi) {
    int row = wr + mi * 16 + fr, h = row >> 6, lr = row & 63;
    aoff[mi] = h * 2048 + lr * 32 + fs;
  }
#pragma unroll
  for (int ni = 0; ni < 4; ++ni) {
    int row = wc + ni * 16 + fr, h = row >> 6, lr = row & 63;
    boff[ni] = h * 2048 + lr * 32 + fs;
  }

  auto STAGE = [&](int s, int kk) {
    const int ko = kk * 32;
#pragma unroll
    for (int j = 0; j < 2; ++j)
      gload16(Ab + (size_t)j * 64 * lda + ko, As + s * ASZ + j * 2048 + tid * 8);
#pragma unroll
    for (int j = 0; j < 2; ++j)
      gload16(Bb + (size_t)j * 64 * ldb + ko, Bs + s * BSZ + j * 2048 + tid * 8);
  };
  auto COMPUTE = [&](int s) {
    const bf16* as = As + s * ASZ;
    const bf16* bs = Bs + s * BSZ;
    bf16x8 af[4], bfm[4];
#pragma unroll
    for (int mi = 0; mi < 4; ++mi) af[mi] = *(const bf16x8*)(as + aoff[mi]);
#pragma unroll
    for (int ni = 0; ni < 4; ++ni) bfm[ni] = *(const bf16x8*)(bs + boff[ni]);
    __builtin_amdgcn_s_setprio(1);
#pragma unroll
    for (int mi = 0; mi < 4; ++mi)
#pragma unroll
      for (int ni = 0; ni < 4; ++ni)
        acc[mi][ni] = __builtin_amdgcn_mfma_f32_16x16x32_bf16(bfm[ni], af[mi], acc[mi][ni], 0, 0, 0);
    __builtin_amdgcn_s_setprio(0);
  };

  const int nk = K >> 5;
  STAGE(0, 0);
  STAGE(1, 1);
  int cur = 0;
  for (int i = 0; i < nk; ++i) {
    if (i < nk - 1) asm volatile("s_waitcnt vmcnt(4)" ::: "memory");
    else            asm volatile("s_waitcnt vmcnt(0)" ::: "memory");
    __builtin_amdgcn_s_barrier();
    asm volatile("" ::: "memory");
    COMPUTE(cur);
    __builtin_amdgcn_s_barrier();
    asm volatile("" ::: "memory");
    if (i + 2 < nk) STAGE(cur, i + 2);
    cur ^= 1;
  }

  const int fq = g * 4;
#pragma unroll
  for (int mi = 0; mi < 4; ++mi) {
    int gr = row0 + wr + mi * 16 + fr;
#pragma unroll
    for (int ni = 0; ni < 4; ++ni) {
      int gc = col0 + wc + ni * 16 + fq;
      float b0 = 0, b1 = 0, b2 = 0, b3 = 0;
      if (bias) {
        float4 bv = *reinterpret_cast<const float4*>(bias + gc);
        b0 = bv.x; b1 = bv.y; b2 = bv.z; b3 = bv.w;
      }
      float v0 = acc[mi][ni][0] + b0, v1 = acc[mi][ni][1] + b1;
      float v2 = acc[mi][ni][2] + b2, v3 = acc[mi][ni][3] + b3;
      if (ob) {
        ushort4 u; u.x = f2b(v0); u.y = f2b(v1); u.z = f2b(v2); u.w = f2b(v3);
        *reinterpret_cast<ushort4*>((bf16*)Cv + (size_t)gr * N + gc) = u;
      } else {
        float4 o; o.x = v0; o.y = v1; o.z = v2; o.w = v3;
        *reinterpret_cast<float4*>((float*)Cv + (size_t)gr * N + gc) = o;
      }
    }
  }
}

// ------------- 8-phase half-tile-pipelined GEMM (B^T), 256², 8 waves --------
// EXPERIMENT (GEMM3 only).  BK=64, 2 K-tiles/iter, LDS = [2 buf][2 half]
// (128 rows x 64 k) per operand = 128 KB.  Per phase: {ds_read one C-quadrant
// subtile || stage ONE half-tile -> just-freed buffer; barrier; lgkmcnt(0)+
// sched_barrier; setprio 16 MFMA; barrier}.  Staging: ph0-3 stage tile v=2j+1
// -> buf1 (A-halves FIRST: deep slack for HBM; B-halves last: L2-resident
// weights); ph4-7 stage tile 2j+2 -> buf0.  Waits: vmcnt(2) after the stage
// at ph0/ph4 (drains the tile about to be computed, keeps the 2 just-issued
// loads in flight — never drains to 0 except the final tile).  Zero-conflict
// swizzle: store source slot = (tid&7)^((tid>>3)&7); read slot = (kk*4+g)^
// (fr&7) (rows are 128 B -> bank = col-only; 2 lanes/column = free 2-way).
template<int HAS_BIAS>
__global__ __launch_bounds__(512, 1) void k_gemm8q(
    const bf16* __restrict__ A, const bf16* __restrict__ Bt,
    float* __restrict__ C, const float* __restrict__ bias,
    int N, int K, int lda, int ldb, int nx) {
  __shared__ bf16 As[2][2][8192];   // [buf][half][128 rows * 64 k]
  __shared__ bf16 Bs[2][2][8192];
  const int tid = threadIdx.x, w = tid >> 6, l = tid & 63;
  const int wm = w >> 2, wn = w & 3;      // 2M x 4N waves; wave tile 128x64

  int bid = blockIdx.x;
  { int nwg = gridDim.x; int q = nwg >> 3, r = nwg & 7;
    int xcd = bid & 7, li = bid >> 3;
    bid = (xcd < r ? xcd * (q + 1) : r * (q + 1) + (xcd - r) * q) + li; }
  const int bx = bid % nx, by = bid / nx;
  const int row0 = by * 256, col0 = bx * 256;

  // staging: thread covers 16B; gload j covers rows [j*64, +64) of a half
  const int srow  = tid >> 3;
  const int sslot = ((tid & 7) ^ ((tid >> 3) & 7)) * 8;   // pre-swizzled src
  const bf16* Ag = A  + (size_t)(row0 + srow) * lda + sslot;
  const bf16* Bg = Bt + (size_t)(col0 + srow) * ldb + sslot;

  const int fr = l & 15, g = l >> 4;
  const int fs0 = (g ^ (fr & 7)) * 8;          // kk=0 read slot (elems)
  const int fs1 = ((4 + g) ^ (fr & 7)) * 8;    // kk=1

  f32x4 acc[8][4] = {};   // [qm*4+mi][qn*2+nj]

#define SA8(d, hh, t) { \
    gload16(Ag + (size_t)((hh) * 128) * lda + (t) * 64,      &As[d][hh][tid * 8]); \
    gload16(Ag + (size_t)((hh) * 128 + 64) * lda + (t) * 64, &As[d][hh][4096 + tid * 8]); }
#define SB8(d, hh, t) { \
    gload16(Bg + (size_t)((hh) * 128) * ldb + (t) * 64,      &Bs[d][hh][tid * 8]); \
    gload16(Bg + (size_t)((hh) * 128 + 64) * ldb + (t) * 64, &Bs[d][hh][4096 + tid * 8]); }

#define RD8(d, qm, qn) \
    const bf16* ah = &As[d][wm][(qm) * 4096]; \
    const bf16* bh = &Bs[d][wn >> 1][(wn & 1) * 4096 + (qn) * 2048]; \
    bf16x8 af[4][2], bv[2][2]; \
    _Pragma("unroll") for (int mi = 0; mi < 4; ++mi) { int ro = (mi * 16 + fr) * 64; \
      af[mi][0] = *(const bf16x8*)(ah + ro + fs0); \
      af[mi][1] = *(const bf16x8*)(ah + ro + fs1); } \
    _Pragma("unroll") for (int nj = 0; nj < 2; ++nj) { int ro = (nj * 16 + fr) * 64; \
      bv[nj][0] = *(const bf16x8*)(bh + ro + fs0); \
      bv[nj][1] = *(const bf16x8*)(bh + ro + fs1); }

#define MM8(qm, qn) \
    __builtin_amdgcn_s_setprio(1); \
    _Pragma("unroll") for (int mi = 0; mi < 4; ++mi) \
      _Pragma("unroll") for (int nj = 0; nj < 2; ++nj) { \
        acc[(qm)*4+mi][(qn)*2+nj] = __builtin_amdgcn_mfma_f32_16x16x32_bf16( \
            bv[nj][0], af[mi][0], acc[(qm)*4+mi][(qn)*2+nj], 0, 0, 0); \
        acc[(qm)*4+mi][(qn)*2+nj] = __builtin_amdgcn_mfma_f32_16x16x32_bf16( \
            bv[nj][1], af[mi][1], acc[(qm)*4+mi][(qn)*2+nj], 0, 0, 0); } \
    __builtin_amdgcn_s_setprio(0);

#define LGKM0 \
    asm volatile("s_waitcnt lgkmcnt(0)" ::: "memory"); \
    __builtin_amdgcn_sched_barrier(0);

  const int nt = K >> 6, ni = nt >> 1;   // nt even (K=1024 -> 16, 8 iters)
  // prologue: tile 0 -> buf0 (8 gloads outstanding)
  SA8(0, 0, 0) SA8(0, 1, 0) SB8(0, 0, 0) SB8(0, 1, 0)

  for (int j = 0; j < ni; ++j) {
    const int v = 2 * j + 1, w2 = 2 * j + 2;
    const bool pw = (w2 < nt);
    // ---- ph0: compute u q(0,0); stage A0(v)->buf1; drain tile u ----
    { SA8(1, 0, v)
      asm volatile("s_waitcnt vmcnt(2)" ::: "memory");
      __builtin_amdgcn_s_barrier();
      RD8(0, 0, 0)
      LGKM0
      MM8(0, 0)
      __builtin_amdgcn_s_barrier();
      asm volatile("" ::: "memory"); }
    // ---- ph1 ----
    { RD8(0, 0, 1)
      SA8(1, 1, v)
      __builtin_amdgcn_s_barrier();
      LGKM0
      MM8(0, 1)
      __builtin_amdgcn_s_barrier();
      asm volatile("" ::: "memory"); }
    // ---- ph2 ----
    { RD8(0, 1, 0)
      SB8(1, 0, v)
      __builtin_amdgcn_s_barrier();
      LGKM0
      MM8(1, 0)
      __builtin_amdgcn_s_barrier();
      asm volatile("" ::: "memory"); }
    // ---- ph3 ----
    { RD8(0, 1, 1)
      SB8(1, 1, v)
      __builtin_amdgcn_s_barrier();
      LGKM0
      MM8(1, 1)
      __builtin_amdgcn_s_barrier();
      asm volatile("" ::: "memory"); }
    // ---- ph4: compute v q(0,0); stage A0(w2)->buf0; drain tile v ----
    { if (pw) SA8(0, 0, w2)
      if (pw) { asm volatile("s_waitcnt vmcnt(2)" ::: "memory"); }
      else    { asm volatile("s_waitcnt vmcnt(0)" ::: "memory"); }
      __builtin_amdgcn_s_barrier();
      RD8(1, 0, 0)
      LGKM0
      MM8(0, 0)
      __builtin_amdgcn_s_barrier();
      asm volatile("" ::: "memory"); }
    // ---- ph5 ----
    { RD8(1, 0, 1)
      if (pw) SA8(0, 1, w2)
      __builtin_amdgcn_s_barrier();
      LGKM0
      MM8(0, 1)
      __builtin_amdgcn_s_barrier();
      asm volatile("" ::: "memory"); }
    // ---- ph6 ----
    { RD8(1, 1, 0)
      if (pw) SB8(0, 0, w2)
      __builtin_amdgcn_s_barrier();
      LGKM0
      MM8(1, 0)
      __builtin_amdgcn_s_barrier();
      asm volatile("" ::: "memory"); }
    // ---- ph7 ----
    { RD8(1, 1, 1)
      if (pw) SB8(0, 1, w2)
      __builtin_amdgcn_s_barrier();
      LGKM0
      MM8(1, 1)
      __builtin_amdgcn_s_barrier();
      asm volatile("" ::: "memory"); }
  }

  // ---- epilogue: gr from fr, 4 consecutive cols per fragment ----
#pragma unroll
  for (int m = 0; m < 8; ++m) {
    int gr = row0 + wm * 128 + (m >> 2) * 64 + (m & 3) * 16 + fr;
#pragma unroll
    for (int n = 0; n < 4; ++n) {
      int gc = col0 + wn * 64 + (n >> 1) * 32 + (n & 1) * 16 + g * 4;
      float b0 = 0, b1 = 0, b2 = 0, b3 = 0;
      if (HAS_BIAS) {
        float4 bb = *reinterpret_cast<const float4*>(bias + gc);
        b0 = bb.x; b1 = bb.y; b2 = bb.z; b3 = bb.w;
      }
      float4 o;
      o.x = acc[m][n][0] + b0; o.y = acc[m][n][1] + b1;
      o.z = acc[m][n][2] + b2; o.w = acc[m][n][3] + b3;
      *reinterpret_cast<float4*>(C + (size_t)gr * N + gc) = o;
    }
  }
#undef SA8
#undef SB8
#undef RD8
#undef MM8
#undef LGKM0
}

// ------------------------------- sampling -----------------------------------
__global__ __launch_bounds__(512) void k_sample(const bf16* __restrict__ C1,
                                                bf16* __restrict__ y) {
  const int wave = threadIdx.x >> 6, lane = threadIdx.x & 63;
  const int row = blockIdx.x * 8 + wave;           // < 14336
  const int b = row / TT, t = row - b * TT;
  const bf16* r1 = C1 + (size_t)row * NCAT;

  float offx, offy;
  {
    ushort2 u = *reinterpret_cast<const ushort2*>(r1 + 1024 + lane * 2);
    offx = __uint_as_float(((unsigned)u.x) << 16);
    offy = __uint_as_float(((unsigned)u.y) << 16);
  }
  float logit;
  {
    unsigned short u = reinterpret_cast<const unsigned short*>(r1)[1152 + lane];
    logit = __uint_as_float(((unsigned)u) << 16);
  }
  float m = fmaxf(logit, __shfl_xor(logit, 1));
  m = fmaxf(m, __shfl_xor(m, 2));
  float e = __expf(logit - m);
  float s = e + __shfl_xor(e, 1);
  s = s + __shfl_xor(s, 2);
  float aw = e / s;

  const float refx = (float)t * (1.0f / 13.0f);
  float ix = refx + offx - 0.5f;
  float xf = floorf(ix);
  float fx = ix - xf;
  float wx = (xf == 0.0f) ? (1.0f - fx) : ((xf == -1.0f) ? fx : 0.0f);

  float iy = offy - 0.5f;
  float yf = floorf(iy);
  float fy = iy - yf;
  int y0 = (int)yf, y1 = y0 + 1;
  float w0 = (y0 >= 0 && y0 < TT) ? (1.0f - fy) : 0.0f;
  float w1 = (y1 >= 0 && y1 < TT) ? fy : 0.0f;
  int i0 = max(0, min(TT - 1, y0));
  int i1 = max(0, min(TT - 1, y1));
  float cw0 = aw * wx * w0;
  float cw1 = aw * wx * w1;

  const bf16* vb = C1 + (size_t)(b * TT) * NCAT;
  const int hofs = (lane & 32) ? 8 : 0;
  const int cofs = (lane & 31) * 2;
  float acc0[8], acc1[8];
#pragma unroll
  for (int h = 0; h < 8; ++h) { acc0[h] = 0.0f; acc1[h] = 0.0f; }
#pragma unroll
  for (int j = 0; j < 32; ++j) {
    const int src = j + (lane & 32);
    float c0 = __shfl(cw0, src);
    float c1 = __shfl(cw1, src);
    int a0 = __shfl(i0, src);
    int a1 = __shfl(i1, src);
    const int hb = j >> 2;
    const int ho = (hb + hofs) * 64 + cofs;
    ushort2 u0 = *reinterpret_cast<const ushort2*>(
        reinterpret_cast<const unsigned short*>(vb) + (size_t)a0 * NCAT + ho);
    ushort2 u1 = *reinterpret_cast<const ushort2*>(
        reinterpret_cast<const unsigned short*>(vb) + (size_t)a1 * NCAT + ho);
    float v00 = __uint_as_float(((unsigned)u0.x) << 16);
    float v01 = __uint_as_float(((unsigned)u0.y) << 16);
    float v10 = __uint_as_float(((unsigned)u1.x) << 16);
    float v11 = __uint_as_float(((unsigned)u1.y) << 16);
    acc0[hb] = fmaf(c0, v00, fmaf(c1, v10, acc0[hb]));
    acc1[hb] = fmaf(c0, v01, fmaf(c1, v11, acc1[hb]));
  }
#pragma unroll
  for (int hb = 0; hb < 8; ++hb) {
    ushort2 o;
    o.x = f2b(acc0[hb]);
    o.y = f2b(acc1[hb]);
    *reinterpret_cast<ushort2*>(
        reinterpret_cast<unsigned short*>(y) +
        (size_t)row * DM + (hb + hofs) * 64 + cofs) = o;
  }
}

// ------------------------------- launcher -----------------------------------
extern "C" void kernel_launch(void* const* d_in, const int* in_sizes, int n_in,
                              void* d_out, int out_size, void* d_ws, size_t ws_size,
                              hipStream_t stream) {
  (void)in_sizes; (void)n_in; (void)out_size; (void)ws_size;
  const float* x       = (const float*)d_in[0];
  const float* W_value = (const float*)d_in[1];
  const float* b_value = (const float*)d_in[2];
  const float* W_off   = (const float*)d_in[3];
  const float* b_off   = (const float*)d_in[4];
  const float* W_attn  = (const float*)d_in[5];
  const float* b_attn  = (const float*)d_in[6];
  const float* W_out   = (const float*)d_in[7];
  const float* b_out   = (const float*)d_in[8];
  const float* W_proj  = (const float*)d_in[9];
  const float* b_proj  = (const float*)d_in[10];

  char* ws = (char*)d_ws;
  bf16*  x_bf    = (bf16*)(ws);                    // 29,360,128 B
  bf16*  y_bf    = x_bf;                           // alias (x dead after GEMM1)
  bf16*  C1      = (bf16*)(ws + 29360128);         // 36,700,160 B
  bf16*  Wcat_t  = (bf16*)(ws + 66060288);         //  2,621,440 B
  float* bcat    = (float*)(ws + 68681728);        //      5,120 B
  bf16*  Wout_b  = (bf16*)(ws + 68686848);         //  2,097,152 B
  bf16*  Wproj_t = (bf16*)(ws + 70784000);         //  2,097,152 B
  bf16*  Wc_t    = (bf16*)(ws + 72881152);         //  2,097,152 B
  float* bcomb   = (float*)(ws + 74978304);        //      4,096 B

  // -- 1: all conversions / transposes / biases / x->bf16 --
  k_prep_all<<<dim3(32, 137), 256, 0, stream>>>(
      x, W_value, W_off, W_attn, W_proj, W_out,
      b_value, b_off, b_attn, b_out, b_proj,
      x_bf, Wcat_t, Wproj_t, Wout_b, bcat, bcomb);

  // -- 2: GEMM1 (x@Wcat -> C1, 1120 blocks) + Wc = (Wout@Wproj)^T (64 blocks) --
  k_gemm_dual<1, 1><<<1120 + 64, 256, 0, stream>>>(
      x_bf, Wcat_t, C1, bcat, NCAT, DM, DM, DM, NCAT / 128, 1120,
      Wproj_t, Wout_b, Wc_t, nullptr, 1024, 1024, 1024, 1024, 8);

  // -- 3: deformable sampling + head combine -> y (bf16) --
  k_sample<<<ROWS / 8, 512, 0, stream>>>(C1, y_bf);

  // -- 4: final GEMM (EXPERIMENT: 8-phase 256² kernel, 224 blocks = 1 round) --
  k_gemm8q<1><<<224, 512, 0, stream>>>(
      y_bf, Wc_t, (float*)d_out, bcomb, DM, DM, DM, DM, 4);
}